// Round 1
// baseline (100.128 us; speedup 1.0000x reference)
//
#include <hip/hip_runtime.h>

// MSEBPRLoss: total = sum_{t_j > t_i} [0.5*softplus(x_i - x_j) + 0.5*(x_i - t_i)^2]
// out = total * 2/N^2.  softplus(d) = ln2 * log2(1 + exp2(x_i*L2E) * exp2(-x_j*L2E))
// => precompute E_i = exp2(x_i*L2E) per-i (regs) and e_j = exp2(-x_j*L2E) per-j (LDS):
// inner loop has ONE v_log_f32 + 6 full-rate VALU ops per pair.

#define N_ELEM 16384
#define BLOCK  256
#define TI     4                         // i-values per thread
#define JCHUNK 256                       // j-values per block
#define NIB    (N_ELEM / (BLOCK * TI))   // 16 i-chunks
#define NJB    (N_ELEM / JCHUNK)         // 64 j-chunks
#define NBLOCKS (NIB * NJB)              // 1024 partials

__device__ __forceinline__ float fexp2(float x) { return __builtin_amdgcn_exp2f(x); }
__device__ __forceinline__ float flog2(float x) { return __builtin_amdgcn_logf(x); }

__global__ __launch_bounds__(BLOCK) void
mse_bpr_pair_kernel(const float* __restrict__ input,
                    const float* __restrict__ target,
                    float* __restrict__ partials) {
    const float L2E      = 1.4426950408889634f;   // log2(e)
    const float HALF_LN2 = 0.34657359027997264f;  // 0.5 * ln(2)

    __shared__ float2 jdat[JCHUNK];   // {e_j = exp2(-x_j*L2E), t_j}

    const int tid = threadIdx.x;
    const int jb  = blockIdx.x;       // j-chunk
    const int ib  = blockIdx.y;       // i-chunk

    // Stage this block's j-chunk into LDS with e_j precomputed (1 trans per j per block)
    {
        const int j  = jb * JCHUNK + tid;
        const float xj = input[j];
        const float tj = target[j];
        jdat[tid] = make_float2(fexp2(-xj * L2E), tj);
    }

    // Per-thread i data (registers). i = ib*1024 + k*256 + tid -> coalesced loads.
    float Ei[TI], hm[TI], ti[TI];
#pragma unroll
    for (int k = 0; k < TI; ++k) {
        const int i  = ib * (BLOCK * TI) + k * BLOCK + tid;
        const float xi = input[i];
        const float t  = target[i];
        Ei[k] = fexp2(xi * L2E);
        const float d = xi - t;
        hm[k] = 0.5f * d * d;         // 0.5 * mse_i, hoisted out of the pair loop
        ti[k] = t;
    }
    __syncthreads();

    float acc[TI] = {0.f, 0.f, 0.f, 0.f};
#pragma unroll 8
    for (int j = 0; j < JCHUNK; ++j) {
        const float2 jt = jdat[j];    // broadcast read: all lanes same address, no conflict
#pragma unroll
        for (int k = 0; k < TI; ++k) {
            const float e = Ei[k] * jt.x;                       // exp(x_i - x_j)
            const float l = flog2(1.0f + e);                    // log2(1+e)
            const float x = __builtin_fmaf(l, HALF_LN2, hm[k]); // 0.5*softplus + 0.5*mse_i
            acc[k] += (jt.y > ti[k]) ? x : 0.0f;                // mask: t_j > t_i
        }
    }

    // Reduce TI accs -> wave -> block
    float v = (acc[0] + acc[1]) + (acc[2] + acc[3]);
#pragma unroll
    for (int off = 32; off > 0; off >>= 1)
        v += __shfl_down(v, off, 64);

    __shared__ float wsum[BLOCK / 64];
    if ((tid & 63) == 0) wsum[tid >> 6] = v;
    __syncthreads();
    if (tid == 0)
        partials[ib * NJB + jb] = (wsum[0] + wsum[1]) + (wsum[2] + wsum[3]);
}

__global__ __launch_bounds__(256) void
mse_bpr_reduce_kernel(const float* __restrict__ partials, float* __restrict__ out) {
    const int tid = threadIdx.x;
    float v = 0.f;
#pragma unroll
    for (int idx = tid; idx < NBLOCKS; idx += 256)
        v += partials[idx];
#pragma unroll
    for (int off = 32; off > 0; off >>= 1)
        v += __shfl_down(v, off, 64);

    __shared__ float wsum[4];
    if ((tid & 63) == 0) wsum[tid >> 6] = v;
    __syncthreads();
    if (tid == 0) {
        const float total = (wsum[0] + wsum[1]) + (wsum[2] + wsum[3]);
        const float scale = 2.0f / ((float)N_ELEM * (float)N_ELEM);
        out[0] = total * scale;
    }
}

extern "C" void kernel_launch(void* const* d_in, const int* in_sizes, int n_in,
                              void* d_out, int out_size, void* d_ws, size_t ws_size,
                              hipStream_t stream) {
    const float* input  = (const float*)d_in[0];
    const float* target = (const float*)d_in[1];
    float* out      = (float*)d_out;
    float* partials = (float*)d_ws;   // NBLOCKS floats = 4 KB

    dim3 grid(NJB, NIB);
    mse_bpr_pair_kernel<<<grid, BLOCK, 0, stream>>>(input, target, partials);
    mse_bpr_reduce_kernel<<<1, 256, 0, stream>>>(partials, out);
}

// Round 2
// 91.323 us; speedup vs baseline: 1.0964x; 1.0964x over previous
//
#include <hip/hip_runtime.h>

// MSEBPRLoss, round 2: log-of-product trick.
//   total = sum_{t_j > t_i} [ HALF_LN2*log2(1+e_ij) + hm_i ],  e_ij = exp(x_i-x_j)
// Per pair: factor = fma(Ei, ej, 1.0); masked to 1.0; p *= f; cnt += mask.
// One v_log_f32 per 8 pairs (product grouping, max factor ~2^12 -> p <= 2^96, no overflow).
// MSE term = hm_i * count_i accumulated as integer carry-adds.
// Single kernel; block partials combined with HW float atomic (unsafeAtomicAdd).

#define N_ELEM 16384
#define BLOCK  256
#define TI     4                         // i-values per thread
#define JCHUNK 256                       // j-values per block
#define GRP    8                         // pairs per product before log2
#define NIB    (N_ELEM / (BLOCK * TI))   // 16 i-chunks
#define NJB    (N_ELEM / JCHUNK)         // 64 j-chunks

__device__ __forceinline__ float fexp2(float x) { return __builtin_amdgcn_exp2f(x); }
__device__ __forceinline__ float flog2(float x) { return __builtin_amdgcn_logf(x); }

__global__ __launch_bounds__(BLOCK) void
mse_bpr_pair_kernel(const float* __restrict__ input,
                    const float* __restrict__ target,
                    float* __restrict__ out) {
    const float L2E      = 1.4426950408889634f;   // log2(e)
    const float HALF_LN2 = 0.34657359027997264f;  // 0.5 * ln(2)

    __shared__ float2 jdat[JCHUNK];   // {e_j = exp2(-x_j*L2E), t_j}

    const int tid = threadIdx.x;
    const int jb  = blockIdx.x;       // j-chunk
    const int ib  = blockIdx.y;       // i-chunk

    // Stage j-chunk into LDS with e_j precomputed
    {
        const int j  = jb * JCHUNK + tid;
        const float xj = input[j];
        const float tj = target[j];
        jdat[tid] = make_float2(fexp2(-xj * L2E), tj);
    }

    // Per-thread i data (registers); coalesced loads.
    float Ei[TI], hm[TI], ti[TI];
#pragma unroll
    for (int k = 0; k < TI; ++k) {
        const int i  = ib * (BLOCK * TI) + k * BLOCK + tid;
        const float xi = input[i];
        const float t  = target[i];
        Ei[k] = fexp2(xi * L2E);
        const float d = xi - t;
        hm[k] = 0.5f * d * d;
        ti[k] = t;
    }
    __syncthreads();

    float logacc[TI] = {0.f, 0.f, 0.f, 0.f};
    int   cnt[TI]    = {0, 0, 0, 0};

    for (int jg = 0; jg < JCHUNK; jg += GRP) {
        float p[TI] = {1.f, 1.f, 1.f, 1.f};
#pragma unroll
        for (int jj = 0; jj < GRP; ++jj) {
            const float2 jt = jdat[jg + jj];   // broadcast read, no bank conflict
#pragma unroll
            for (int k = 0; k < TI; ++k) {
                const float f = __builtin_fmaf(Ei[k], jt.x, 1.0f);  // 1 + exp(x_i - x_j)
                const bool  m = (jt.y > ti[k]);
                p[k]  *= m ? f : 1.0f;       // cmp + cndmask + mul
                cnt[k] += m;                 // carry-add off the same cmp
            }
        }
#pragma unroll
        for (int k = 0; k < TI; ++k)
            logacc[k] += flog2(p[k]);        // 1 trans per 8 pairs per k
    }

    // Per-thread combine: HALF_LN2 * sum(log2) + sum hm_i * count_i
    float v = HALF_LN2 * ((logacc[0] + logacc[1]) + (logacc[2] + logacc[3]));
#pragma unroll
    for (int k = 0; k < TI; ++k)
        v = __builtin_fmaf(hm[k], (float)cnt[k], v);

    // Wave reduce
#pragma unroll
    for (int off = 32; off > 0; off >>= 1)
        v += __shfl_down(v, off, 64);

    __shared__ float wsum[BLOCK / 64];
    if ((tid & 63) == 0) wsum[tid >> 6] = v;
    __syncthreads();
    if (tid == 0) {
        const float scale = 2.0f / ((float)N_ELEM * (float)N_ELEM);
        const float part  = ((wsum[0] + wsum[1]) + (wsum[2] + wsum[3])) * scale;
        unsafeAtomicAdd(out, part);          // HW global_atomic_add_f32, 1024 adds total
    }
}

extern "C" void kernel_launch(void* const* d_in, const int* in_sizes, int n_in,
                              void* d_out, int out_size, void* d_ws, size_t ws_size,
                              hipStream_t stream) {
    const float* input  = (const float*)d_in[0];
    const float* target = (const float*)d_in[1];
    float* out = (float*)d_out;

    hipMemsetAsync(out, 0, sizeof(float), stream);   // d_out is poisoned 0xAA pre-launch
    dim3 grid(NJB, NIB);
    mse_bpr_pair_kernel<<<grid, BLOCK, 0, stream>>>(input, target, out);
}